// Round 6
// baseline (140.704 us; speedup 1.0000x reference)
//
#include <hip/hip_runtime.h>
#include <cstddef>

#define N_TOK 2048
#define BATCH 2
#define EMB   1024
#define NH    16
#define HD    64
#define NP    16
#define BHN   32
#define CHK   64
#define NCHK  32
#define SCALING 0.125f

typedef __attribute__((ext_vector_type(8))) short short8;
typedef __attribute__((ext_vector_type(4))) float f32x4;

typedef __attribute__((address_space(1))) const void gvoid;
typedef __attribute__((address_space(3))) void lvoid;
__device__ __forceinline__ void gload16(const void* g, void* l) {
  __builtin_amdgcn_global_load_lds((gvoid*)g, (lvoid*)l, 16, 0, 0);
}

__device__ __forceinline__ unsigned short f2bf(float f) {
  unsigned u = __float_as_uint(f);
  u += 0x7FFFu + ((u >> 16) & 1u);
  return (unsigned short)(u >> 16);
}

// ---------------- L1: fused prep (bf16 converts + concat) + pq projection ----------------
__global__ __launch_bounds__(256) void prep_pq_kernel(
    const float* __restrict__ query, const float* __restrict__ Wk,
    const float* __restrict__ Wv, const float* __restrict__ Wo,
    const float* __restrict__ bk, const float* __restrict__ bv,
    const float* __restrict__ pquery, const float* __restrict__ Wpq,
    const float* __restrict__ bpq,
    unsigned short* __restrict__ qbf, unsigned short* __restrict__ wkvbf,
    unsigned short* __restrict__ wobf, float* __restrict__ bkv,
    float* __restrict__ pq_s)
{
  const int b = blockIdx.x, t = threadIdx.x;
  if (b < 512) {
    // ---- pq_proj: r = b>>4 (0..31), seg = b&15 (0..15)
    __shared__ float xs[EMB];
    __shared__ float part[4][64];
    const int r = b >> 4, seg = b & 15;
    const int p = r >> 1, ib = r & 1;
    const int el = t & 63, ks = t >> 6;
    const int e = seg * 64 + el;
    for (int l = t; l < EMB; l += 256) xs[l] = pquery[(size_t)r * EMB + l];
    __syncthreads();
    const float* wrow = &Wpq[(size_t)e * EMB + ks * 256];
    const float* xp = &xs[ks * 256];
    float acc = 0.f;
    #pragma unroll 8
    for (int cc = 0; cc < 256; cc += 4) {
      const float4 w4 = *(const float4*)&wrow[cc];
      acc += xp[cc] * w4.x + xp[cc + 1] * w4.y + xp[cc + 2] * w4.z + xp[cc + 3] * w4.w;
    }
    part[ks][el] = acc;
    __syncthreads();
    if (ks == 0) {
      float s = part[0][el] + part[1][el] + part[2][el] + part[3][el];
      s = (s + bpq[e]) * SCALING;
      const int h = e >> 6, d = e & 63;
      pq_s[((size_t)(ib * NH + h) * NP + p) * HD + d] = s;
    }
  } else {
    // ---- prep streaming converts
    const int tid = (b - 512) * 256 + t;
    const int NT = 1024 * 256;
    for (int i = tid; i < 1835008; i += NT) {
      const float* src; unsigned short* dst; int off;
      if (i < 1048576)      { src = query; dst = qbf;             off = i; }
      else if (i < 1310720) { src = Wk;    dst = wkvbf;           off = i - 1048576; }
      else if (i < 1572864) { src = Wv;    dst = wkvbf + 1048576; off = i - 1310720; }
      else                  { src = Wo;    dst = wobf;            off = i - 1572864; }
      const float4 v = *(const float4*)&src[(size_t)off * 4];
      ushort4 o;
      o.x = f2bf(v.x); o.y = f2bf(v.y); o.z = f2bf(v.z); o.w = f2bf(v.w);
      *(ushort4*)&dst[(size_t)off * 4] = o;
    }
    if (tid < 512) {
      const int j = tid * 4;
      if (j < 1024) *(float4*)&bkv[j] = *(const float4*)&bk[j];
      else          *(float4*)&bkv[j] = *(const float4*)&bv[j - 1024];
    }
  }
}

// ---------------- L2: fused KV-GEMM (128x128, dual bf16 out) + pattn logits ----------------
__global__ __launch_bounds__(256) void kv_pattn_kernel(
    const unsigned short* __restrict__ Xb, const unsigned short* __restrict__ Wb,
    const float* __restrict__ bias, unsigned short* __restrict__ Y0,
    unsigned short* __restrict__ Y1,
    const float* __restrict__ query, const float* __restrict__ pq_s,
    float* __restrict__ pe, float* __restrict__ redm)
{
  __shared__ char smem[22848] __attribute__((aligned(16)));
  const int b = blockIdx.x, t = threadIdx.x;
  if (b < 512) {
    // ---- KV-GEMM: 128x128 tile, M=4096, N=2048, K=1024
    unsigned short* As = (unsigned short*)smem;       // [128][32]
    unsigned short* Bs = As + 4096;                   // [128][32]
    const int m0 = (b >> 4) * 128, n0 = (b & 15) * 128;
    const int lane = t & 63, w = t >> 6, wr = w >> 1, wc = w & 1;
    const int lr = lane & 15, lg = lane >> 4;
    const int srow = t >> 2, scol = (t & 3) << 3;
    f32x4 acc[4][4] = {};
    for (int k0 = 0; k0 < 1024; k0 += 32) {
      gload16(&Xb[(size_t)(m0 + srow) * 1024 + k0 + scol], &As[t * 8]);
      gload16(&Xb[(size_t)(m0 + srow + 64) * 1024 + k0 + scol], &As[2048 + t * 8]);
      gload16(&Wb[(size_t)(n0 + srow) * 1024 + k0 + scol], &Bs[t * 8]);
      gload16(&Wb[(size_t)(n0 + srow + 64) * 1024 + k0 + scol], &Bs[2048 + t * 8]);
      __syncthreads();
      short8 av[4], bv[4];
      #pragma unroll
      for (int m = 0; m < 4; ++m) av[m] = *(const short8*)&As[(wr * 64 + m * 16 + lr) * 32 + lg * 8];
      #pragma unroll
      for (int n = 0; n < 4; ++n) bv[n] = *(const short8*)&Bs[(wc * 64 + n * 16 + lr) * 32 + lg * 8];
      #pragma unroll
      for (int m = 0; m < 4; ++m)
        #pragma unroll
        for (int n = 0; n < 4; ++n)
          acc[m][n] = __builtin_amdgcn_mfma_f32_16x16x32_bf16(av[m], bv[n], acc[m][n], 0, 0, 0);
      __syncthreads();
    }
    unsigned short* dst = (n0 < 1024) ? Y0 : Y1;
    #pragma unroll
    for (int n = 0; n < 4; ++n) {
      const int gcol = n0 + wc * 64 + n * 16 + lr;
      const float bcol = bias[gcol];
      const int lcol = gcol & 1023;
      #pragma unroll
      for (int m = 0; m < 4; ++m) {
        const int row0 = m0 + wr * 64 + m * 16 + lg * 4;
        #pragma unroll
        for (int q = 0; q < 4; ++q)
          dst[(size_t)(row0 + q) * 1024 + lcol] = f2bf(acc[m][n][q] + bcol);
      }
    }
  } else {
    // ---- pattn + fused per-chunk column max
    float (*qs)[68] = (float(*)[68])smem;             // 64x68
    float (*ps)[68] = (float(*)[68])(smem + 17408);   // 16x68
    float (*red)[17] = (float(*)[17])(smem + 21760);  // 16x17
    const int idx = b - 512;
    const int c = idx & 31, bh = idx >> 5;
    const int ib = bh >> 4, h = bh & 15;
    const int i0 = c * CHK;
    for (int l = t; l < CHK * 16; l += 256) {
      const int i = l >> 4, d4 = (l & 15) << 2;
      *(float4*)&qs[i][d4] =
          *(const float4*)&query[((size_t)(i0 + i) * BATCH + ib) * EMB + h * HD + d4];
    }
    {
      const int pp = t >> 4, d4 = (t & 15) << 2;
      *(float4*)&ps[pp][d4] = *(const float4*)&pq_s[((size_t)bh * NP + pp) * HD + d4];
    }
    __syncthreads();
    const int p = t & 15, ig = t >> 4;
    float mx = -3.0e38f;
    for (int rep = 0; rep < 4; ++rep) {
      const int i = rep * 16 + ig;
      float acc = 0.f;
      for (int d = 0; d < HD; ++d) acc += qs[i][d] * ps[p][d];
      pe[(size_t)bh * (N_TOK * NP) + (size_t)(i0 + i) * NP + p] = acc;
      mx = fmaxf(mx, acc);
    }
    red[ig][p] = mx;
    __syncthreads();
    if (t < 16) {
      float m2 = red[0][t];
      #pragma unroll
      for (int g2 = 1; g2 < 16; ++g2) m2 = fmaxf(m2, red[g2][t]);
      redm[((size_t)bh * NCHK + c) * 16 + t] = m2;
    }
  }
}

// ---------------- fused exp + per-chunk totals via MFMA ----------------
__global__ __launch_bounds__(256) void totals_mfma_kernel(
    const unsigned short* __restrict__ Kbf, const unsigned short* __restrict__ Vbf,
    float* __restrict__ pe, const float* __restrict__ redm,
    float* __restrict__ Tk, float* __restrict__ Tv, float* __restrict__ Tsc)
{
  const int c = blockIdx.x, bh = blockIdx.y;
  const int ib = bh >> 4, h = bh & 15;
  const int t = threadIdx.x;
  const int i0 = c * CHK;
  const int lane = t & 63, w = t >> 6;
  const int lr = lane & 15, lg = lane >> 4;

  __shared__ unsigned short KT[64][80];
  __shared__ unsigned short VT[64][80];
  __shared__ unsigned short EbT[16][80];
  __shared__ float Ef[64][20];
  __shared__ float ms[16];
  __shared__ float tspart[4][16];

  if (t < 16) {
    float m2 = -3.0e38f;
    #pragma unroll
    for (int s = 0; s < NCHK; ++s) m2 = fmaxf(m2, redm[((size_t)bh * NCHK + s) * 16 + t]);
    ms[t] = m2;
  }
  __syncthreads();

  #pragma unroll
  for (int it = 0; it < 2; ++it) {
    const int task = t + it * 256;
    const int j = task & 63, dg = task >> 6;
    const size_t g = ((size_t)(i0 + j) * BATCH + ib) * EMB + h * HD + dg * 8;
    const uint4 ku = *(const uint4*)&Kbf[g];
    const uint4 vu = *(const uint4*)&Vbf[g];
    const unsigned short* kk = (const unsigned short*)&ku;
    const unsigned short* vv = (const unsigned short*)&vu;
    #pragma unroll
    for (int e = 0; e < 8; ++e) { KT[dg * 8 + e][j] = kk[e]; VT[dg * 8 + e][j] = vv[e]; }
  }
  {
    const int j = t >> 2, p0 = (t & 3) << 2;
    const size_t gi = (size_t)bh * (N_TOK * NP) + (size_t)(i0 + j) * NP + p0;
    float4 l4 = *(const float4*)&pe[gi];
    l4.x = expf(l4.x - ms[p0]);     l4.y = expf(l4.y - ms[p0 + 1]);
    l4.z = expf(l4.z - ms[p0 + 2]); l4.w = expf(l4.w - ms[p0 + 3]);
    *(float4*)&pe[gi] = l4;
    Ef[j][p0] = l4.x; Ef[j][p0 + 1] = l4.y; Ef[j][p0 + 2] = l4.z; Ef[j][p0 + 3] = l4.w;
    EbT[p0][j] = f2bf(l4.x); EbT[p0 + 1][j] = f2bf(l4.y);
    EbT[p0 + 2][j] = f2bf(l4.z); EbT[p0 + 3][j] = f2bf(l4.w);
  }
  __syncthreads();

  if (t < 64) {
    const int p = t & 15, qq = t >> 4;
    float s = 0.f;
    #pragma unroll
    for (int jj = 0; jj < 16; ++jj) s += Ef[qq * 16 + jj][p];
    tspart[qq][p] = s;
  }

  short8 ae0 = *(const short8*)&EbT[lr][lg * 8];
  short8 ae1 = *(const short8*)&EbT[lr][32 + lg * 8];
  const size_t tb = (size_t)(bh * NCHK + c) * 1024;

  {
    f32x4 ka = {};
    short8 bk0 = *(const short8*)&KT[w * 16 + lr][lg * 8];
    short8 bk1 = *(const short8*)&KT[w * 16 + lr][32 + lg * 8];
    ka = __builtin_amdgcn_mfma_f32_16x16x32_bf16(ae0, bk0, ka, 0, 0, 0);
    ka = __builtin_amdgcn_mfma_f32_16x16x32_bf16(ae1, bk1, ka, 0, 0, 0);
    #pragma unroll
    for (int q = 0; q < 4; ++q) Tk[tb + (lg * 4 + q) * 64 + w * 16 + lr] = ka[q];
  }
  {
    f32x4 va = {};
    short8 av0 = *(const short8*)&VT[w * 16 + lr][lg * 8];
    short8 av1 = *(const short8*)&VT[w * 16 + lr][32 + lg * 8];
    va = __builtin_amdgcn_mfma_f32_16x16x32_bf16(av0, ae0, va, 0, 0, 0);
    va = __builtin_amdgcn_mfma_f32_16x16x32_bf16(av1, ae1, va, 0, 0, 0);
    #pragma unroll
    for (int q = 0; q < 4; ++q) Tv[tb + (w * 16 + lg * 4 + q) * 16 + lr] = va[q];
  }
  __syncthreads();
  if (t < 16)
    Tsc[(size_t)(bh * NCHK + c) * 16 + t] =
        tspart[0][t] + tspart[1][t] + tspart[2][t] + tspart[3][t];
}

// ---------------- exclusive scan over chunks ----------------
__global__ __launch_bounds__(256) void chunk_scan_kernel(
    float* __restrict__ Tk, float* __restrict__ Tv, float* __restrict__ Ts)
{
  const int bh = blockIdx.x, y = blockIdx.y, t = threadIdx.x;
  const int slot = y * 256 + t;
  float* arr = (slot < 1024) ? Tk : Tv;
  const int e = slot & 1023;
  const size_t base = (size_t)bh * (NCHK * 1024) + e;
  float v[NCHK];
  #pragma unroll
  for (int c = 0; c < NCHK; ++c) v[c] = arr[base + (size_t)c * 1024];
  float run = 0.f;
  #pragma unroll
  for (int c = 0; c < NCHK; ++c) { arr[base + (size_t)c * 1024] = run; run += v[c]; }
  if (y == 7 && t < 16) {
    const size_t sb = (size_t)bh * (NCHK * 16) + t;
    float s[NCHK];
    #pragma unroll
    for (int c = 0; c < NCHK; ++c) s[c] = Ts[sb + c * 16];
    float rs = 0.f;
    #pragma unroll
    for (int c = 0; c < NCHK; ++c) { Ts[sb + c * 16] = rs; rs += s[c]; }
  }
}

// ---------------- within-chunk causal attention via MFMA ----------------
__global__ __launch_bounds__(256) void attn_mfma_kernel(
    const unsigned short* __restrict__ qbf, const unsigned short* __restrict__ Kbf,
    const unsigned short* __restrict__ Vbf, const float* __restrict__ pe,
    const float* __restrict__ Tk, const float* __restrict__ Tv,
    const float* __restrict__ Ts, float* __restrict__ aw_buf,
    unsigned short* __restrict__ outpre)
{
  const int c = blockIdx.x, bh = blockIdx.y;
  const int ib = bh >> 4, h = bh & 15;
  const int t = threadIdx.x;
  const int i0 = c * CHK;
  const int lane = t & 63, w = t >> 6;
  const int ws = w * 16;
  const int lr = lane & 15, lg = lane >> 4;
  const int nsl = (w >> 1) + 1;

  __shared__ unsigned short Qb[64][80];
  __shared__ unsigned short Kb[64][80];
  __shared__ unsigned short VT[64][80];
  __shared__ unsigned short Ab[64][80];
  __shared__ unsigned short Eb[64][40];
  __shared__ unsigned short EbT[16][80];
  __shared__ unsigned short Nbt[16][80];
  __shared__ unsigned short Mbt[64][40];
  __shared__ unsigned short Gb[64][40];
  __shared__ float Sbf[16];

  #pragma unroll
  for (int it = 0; it < 2; ++it) {
    const int task = t + it * 256;
    const int i = task >> 3, d0 = (task & 7) << 3;
    const size_t g = ((size_t)(i0 + i) * BATCH + ib) * EMB + h * HD + d0;
    *(uint4*)&Qb[i][d0] = *(const uint4*)&qbf[g];
    *(uint4*)&Kb[i][d0] = *(const uint4*)&Kbf[g];
  }
  #pragma unroll
  for (int it = 0; it < 2; ++it) {
    const int task = t + it * 256;
    const int j = task & 63, dg = task >> 6;
    const size_t g = ((size_t)(i0 + j) * BATCH + ib) * EMB + h * HD + dg * 8;
    const uint4 vu = *(const uint4*)&Vbf[g];
    const unsigned short* vv = (const unsigned short*)&vu;
    #pragma unroll
    for (int e = 0; e < 8; ++e) VT[dg * 8 + e][j] = vv[e];
  }
  {
    const int j = t >> 2, p0 = (t & 3) << 2;
    const float4 e4 = *(const float4*)&pe[(size_t)bh * (N_TOK * NP) + (size_t)(i0 + j) * NP + p0];
    const unsigned short b0 = f2bf(e4.x), b1 = f2bf(e4.y), b2 = f2bf(e4.z), b3 = f2bf(e4.w);
    Eb[j][p0] = b0; Eb[j][p0 + 1] = b1; Eb[j][p0 + 2] = b2; Eb[j][p0 + 3] = b3;
    Eb[j][p0 + 16] = 0; Eb[j][p0 + 17] = 0; Eb[j][p0 + 18] = 0; Eb[j][p0 + 19] = 0;
    EbT[p0][j] = b0; EbT[p0 + 1][j] = b1; EbT[p0 + 2][j] = b2; EbT[p0 + 3][j] = b3;
  }
  {
    const int p = t >> 4, d0 = (t & 15) << 2;
    const float4 v = *(const float4*)&Tk[(size_t)(bh * NCHK + c) * 1024 + p * 64 + d0];
    Nbt[p][d0] = f2bf(v.x); Nbt[p][d0 + 1] = f2bf(v.y);
    Nbt[p][d0 + 2] = f2bf(v.z); Nbt[p][d0 + 3] = f2bf(v.w);
  }
  {
    const int d = t >> 2, p0 = (t & 3) << 2;
    const float4 v = *(const float4*)&Tv[(size_t)(bh * NCHK + c) * 1024 + d * 16 + p0];
    Mbt[d][p0] = f2bf(v.x); Mbt[d][p0 + 1] = f2bf(v.y);
    Mbt[d][p0 + 2] = f2bf(v.z); Mbt[d][p0 + 3] = f2bf(v.w);
    Mbt[d][p0 + 16] = 0; Mbt[d][p0 + 17] = 0; Mbt[d][p0 + 18] = 0; Mbt[d][p0 + 19] = 0;
  }
  if (t < 16) Sbf[t] = Ts[(size_t)(bh * NCHK + c) * 16 + t];
  __syncthreads();

  short8 avq0 = *(const short8*)&Qb[ws + lr][lg * 8];
  short8 avq1 = *(const short8*)&Qb[ws + lr][32 + lg * 8];

  f32x4 sacc[4] = {};
  for (int n = 0; n <= w; ++n) {
    short8 bk0 = *(const short8*)&Kb[n * 16 + lr][lg * 8];
    short8 bk1 = *(const short8*)&Kb[n * 16 + lr][32 + lg * 8];
    sacc[n] = __builtin_amdgcn_mfma_f32_16x16x32_bf16(avq0, bk0, sacc[n], 0, 0, 0);
    sacc[n] = __builtin_amdgcn_mfma_f32_16x16x32_bf16(avq1, bk1, sacc[n], 0, 0, 0);
  }
  #pragma unroll
  for (int q = 0; q < 4; ++q)
    if (lr >= lg * 4 + q) sacc[w][q] = 0.f;
  for (int n = 0; n < 2 * nsl; ++n)
    #pragma unroll
    for (int q = 0; q < 4; ++q)
      Ab[ws + lg * 4 + q][n * 16 + lr] = f2bf(sacc[n][q]);

  short8 bve0 = *(const short8*)&EbT[lr][lg * 8];
  short8 bve1 = *(const short8*)&EbT[lr][32 + lg * 8];

  f32x4 wacc = {};
  {
    short8 bn0 = *(const short8*)&Nbt[lr][lg * 8];
    short8 bn1 = *(const short8*)&Nbt[lr][32 + lg * 8];
    wacc = __builtin_amdgcn_mfma_f32_16x16x32_bf16(avq0, bn0, wacc, 0, 0, 0);
    wacc = __builtin_amdgcn_mfma_f32_16x16x32_bf16(avq1, bn1, wacc, 0, 0, 0);
  }
  for (int ks = 0; ks < nsl; ++ks) {
    short8 aa = *(const short8*)&Ab[ws + lr][ks * 32 + lg * 8];
    wacc = __builtin_amdgcn_mfma_f32_16x16x32_bf16(aa, ks ? bve1 : bve0, wacc, 0, 0, 0);
  }
  const float s0 = Sbf[lr];
  f32x4 scacc = {s0, s0, s0, s0};
  for (int ks = 0; ks < nsl; ++ks) {
    const int jb = ks * 32 + lg * 8;
    const int irow = ws + lr;
    short8 ones;
    #pragma unroll
    for (int e = 0; e < 8; ++e) ones[e] = (short)((jb + e < irow) ? 0x3F80 : 0);
    scacc = __builtin_amdgcn_mfma_f32_16x16x32_bf16(ones, ks ? bve1 : bve0, scacc, 0, 0, 0);
  }

  const size_t awbase = (size_t)bh * (N_TOK * NP) + (size_t)i0 * NP;
  #pragma unroll
  for (int q = 0; q < 4; ++q) {
    const int il = lg * 4 + q;
    const float ssum = scacc[q];
    const float ssafe = (ssum > 0.f) ? ssum : 1.f;
    const float wv = SCALING * wacc[q] / ssafe;
    float m = wv;
    #pragma unroll
    for (int off = 1; off < 16; off <<= 1) m = fmaxf(m, __shfl_xor(m, off, 64));
    const float e = expf(wv - m);
    float ss = e;
    #pragma unroll
    for (int off = 1; off < 16; off <<= 1) ss += __shfl_xor(ss, off, 64);
    const float aw = e / ss;
    aw_buf[awbase + (size_t)(ws + il) * NP + lr] = aw;
    const float g = aw / ssafe;
    Gb[ws + il][lr] = f2bf(g);
    Gb[ws + il][lr + 16] = 0;
  }

  short8 ga = *(const short8*)&Gb[ws + lr][lg * 8];
  f32x4 bacc[4] = {};
  for (int n = 0; n <= w; ++n) {
    short8 be = *(const short8*)&Eb[n * 16 + lr][lg * 8];
    bacc[n] = __builtin_amdgcn_mfma_f32_16x16x32_bf16(ga, be, bacc[n], 0, 0, 0);
  }
  #pragma unroll
  for (int q = 0; q < 4; ++q)
    if (lr >= lg * 4 + q) bacc[w][q] = 0.f;
  for (int n = 0; n < 2 * nsl; ++n)
    #pragma unroll
    for (int q = 0; q < 4; ++q)
      Ab[ws + lg * 4 + q][n * 16 + lr] = f2bf(bacc[n][q]);

  f32x4 oacc[4] = {};
  #pragma unroll
  for (int dn = 0; dn < 4; ++dn) {
    short8 bm = *(const short8*)&Mbt[dn * 16 + lr][lg * 8];
    oacc[dn] = __builtin_amdgcn_mfma_f32_16x16x32_bf16(ga, bm, oacc[dn], 0, 0, 0);
  }
  for (int ks = 0; ks < nsl; ++ks) {
    short8 ab = *(const short8*)&Ab[ws + lr][ks * 32 + lg * 8];
    #pragma unroll
    for (int dn = 0; dn < 4; ++dn) {
      short8 bv = *(const short8*)&VT[dn * 16 + lr][ks * 32 + lg * 8];
      oacc[dn] = __builtin_amdgcn_mfma_f32_16x16x32_bf16(ab, bv, oacc[dn], 0, 0, 0);
    }
  }

  #pragma unroll
  for (int dn = 0; dn < 4; ++dn)
    #pragma unroll
    for (int q = 0; q < 4; ++q) {
      const int i = ws + lg * 4 + q;
      const int d = dn * 16 + lr;
      outpre[((size_t)(i0 + i) * BATCH + ib) * EMB + h * HD + d] = f2bf(oacc[dn][q]);
    }
}

// ---------------- L6: fused O-GEMM (128x64 tiles, f32 out) + aw mean over heads ----------------
__global__ __launch_bounds__(256) void o_aw_kernel(
    const unsigned short* __restrict__ Xb, const unsigned short* __restrict__ Wb,
    const float* __restrict__ bias, float* __restrict__ Yf,
    const float* __restrict__ aw_buf, float* __restrict__ out_aw)
{
  __shared__ char smem[12288] __attribute__((aligned(16)));
  const int b = blockIdx.x, t = threadIdx.x;
  if (b < 512) {
    unsigned short* As = (unsigned short*)smem;   // [128][32]
    unsigned short* Bs = As + 4096;               // [64][32]
    const int m0 = (b >> 4) * 128, n0 = (b & 15) * 64;
    const int lane = t & 63, w = t >> 6, wr = w >> 1, wc = w & 1;
    const int lr = lane & 15, lg = lane >> 4;
    const int srow = t >> 2, scol = (t & 3) << 3;
    f32x4 acc[4][2] = {};
    for (int k0 = 0; k0 < 1024; k0 += 32) {
      gload16(&Xb[(size_t)(m0 + srow) * 1024 + k0 + scol], &As[t * 8]);
      gload16(&Xb[(size_t)(m0 + srow + 64) * 1024 + k0 + scol], &As[2048 + t * 8]);
      gload16(&Wb[(size_t)(n0 + srow) * 1024 + k0 + scol], &Bs[t * 8]);
      __syncthreads();
      short8 av[4], bv[2];
      #pragma unroll
      for (int m = 0; m < 4; ++m) av[m] = *(const short8*)&As[(wr * 64 + m * 16 + lr) * 32 + lg * 8];
      #pragma unroll
      for (int n = 0; n < 2; ++n) bv[n] = *(const short8*)&Bs[(wc * 32 + n * 16 + lr) * 32 + lg * 8];
      #pragma unroll
      for (int m = 0; m < 4; ++m)
        #pragma unroll
        for (int n = 0; n < 2; ++n)
          acc[m][n] = __builtin_amdgcn_mfma_f32_16x16x32_bf16(av[m], bv[n], acc[m][n], 0, 0, 0);
      __syncthreads();
    }
    #pragma unroll
    for (int n = 0; n < 2; ++n) {
      const int gcol = n0 + wc * 32 + n * 16 + lr;
      const float bcol = bias[gcol];
      #pragma unroll
      for (int m = 0; m < 4; ++m) {
        const int row0 = m0 + wr * 64 + m * 16 + lg * 4;
        #pragma unroll
        for (int q = 0; q < 4; ++q)
          Yf[(size_t)(row0 + q) * 1024 + gcol] = acc[m][n][q] + bcol;
      }
    }
  } else {
    const int idx = (b - 512) * 256 + t;
    const int p = idx & 15;
    const int i = (idx >> 4) & 2047;
    const int ib = idx >> 15;
    float s = 0.f;
    for (int hh = 0; hh < NH; ++hh)
      s += aw_buf[((size_t)(ib * NH + hh) * N_TOK + i) * NP + p];
    out_aw[idx] = s * (1.f / 16.f);
  }
}

extern "C" void kernel_launch(void* const* d_in, const int* in_sizes, int n_in,
                              void* d_out, int out_size, void* d_ws, size_t ws_size,
                              hipStream_t stream) {
  const float* query  = (const float*)d_in[0];
  const float* pquery = (const float*)d_in[1];
  const float* Wpq    = (const float*)d_in[2];
  const float* bpq    = (const float*)d_in[3];
  const float* Wk     = (const float*)d_in[4];
  const float* bk     = (const float*)d_in[5];
  const float* Wv     = (const float*)d_in[6];
  const float* bv     = (const float*)d_in[7];
  const float* Wo     = (const float*)d_in[8];
  const float* bo     = (const float*)d_in[9];
  float* out = (float*)d_out;
  float* ws  = (float*)d_ws;

  float* pq_s   = ws;                       // 32768
  float* pe     = pq_s + 32768;             // 1048576
  float* aw_buf = pe + 1048576;             // 1048576
  float* Tk     = aw_buf + 1048576;         // 1048576
  float* Tv     = Tk + 1048576;             // 1048576
  float* Ts     = Tv + 1048576;             // 16384
  float* redm   = Ts + 16384;               // 16384
  float* bkv    = redm + 16384;             // 2048
  unsigned short* qbf   = (unsigned short*)(bkv + 2048);
  unsigned short* Kbf   = qbf + 4194304;
  unsigned short* Vbf   = Kbf + 4194304;
  unsigned short* wkvbf = Vbf + 4194304;    // 2097152
  unsigned short* wobf  = wkvbf + 2097152;  // 1048576
  unsigned short* opbf  = wobf + 1048576;   // 4194304

  prep_pq_kernel<<<1536, 256, 0, stream>>>(query, Wk, Wv, Wo, bk, bv, pquery, Wpq, bpq,
                                           qbf, wkvbf, wobf, bkv, pq_s);
  kv_pattn_kernel<<<1536, 256, 0, stream>>>(qbf, wkvbf, bkv, Kbf, Vbf, query, pq_s, pe, redm);
  totals_mfma_kernel<<<dim3(NCHK, BHN), 256, 0, stream>>>(Kbf, Vbf, pe, redm, Tk, Tv, Ts);
  chunk_scan_kernel<<<dim3(BHN, 8), 256, 0, stream>>>(Tk, Tv, Ts);
  attn_mfma_kernel<<<dim3(NCHK, BHN), 256, 0, stream>>>(qbf, Kbf, Vbf, pe, Tk, Tv, Ts,
                                                        aw_buf, opbf);
  o_aw_kernel<<<768, 256, 0, stream>>>(opbf, wobf, bo, out, aw_buf, out + 4194304);
}

// Round 7
// 122.658 us; speedup vs baseline: 1.1471x; 1.1471x over previous
//
#include <hip/hip_runtime.h>
#include <cstddef>

#define N_TOK 2048
#define BATCH 2
#define EMB   1024
#define NH    16
#define HD    64
#define NP    16
#define BHN   32
#define CHK   64
#define NCHK  32
#define SCALING 0.125f

typedef __attribute__((ext_vector_type(8))) short short8;
typedef __attribute__((ext_vector_type(4))) float f32x4;

typedef __attribute__((address_space(1))) const void gvoid;
typedef __attribute__((address_space(3))) void lvoid;
__device__ __forceinline__ void gload16(const void* g, void* l) {
  __builtin_amdgcn_global_load_lds((gvoid*)g, (lvoid*)l, 16, 0, 0);
}

__device__ __forceinline__ unsigned short f2bf(float f) {
  unsigned u = __float_as_uint(f);
  u += 0x7FFFu + ((u >> 16) & 1u);
  return (unsigned short)(u >> 16);
}

// ---------------- L1: fused prep (bf16 converts + concat) + pq projection ----------------
__global__ __launch_bounds__(256) void prep_pq_kernel(
    const float* __restrict__ query, const float* __restrict__ Wk,
    const float* __restrict__ Wv, const float* __restrict__ Wo,
    const float* __restrict__ bk, const float* __restrict__ bv,
    const float* __restrict__ pquery, const float* __restrict__ Wpq,
    const float* __restrict__ bpq,
    unsigned short* __restrict__ qbf, unsigned short* __restrict__ wkvbf,
    unsigned short* __restrict__ wobf, float* __restrict__ bkv,
    float* __restrict__ pq_s)
{
  const int b = blockIdx.x, t = threadIdx.x;
  if (b < 512) {
    __shared__ float xs[EMB];
    __shared__ float part[4][64];
    const int r = b >> 4, seg = b & 15;
    const int p = r >> 1, ib = r & 1;
    const int el = t & 63, ks = t >> 6;
    const int e = seg * 64 + el;
    for (int l = t; l < EMB; l += 256) xs[l] = pquery[(size_t)r * EMB + l];
    __syncthreads();
    const float* wrow = &Wpq[(size_t)e * EMB + ks * 256];
    const float* xp = &xs[ks * 256];
    float acc = 0.f;
    #pragma unroll 8
    for (int cc = 0; cc < 256; cc += 4) {
      const float4 w4 = *(const float4*)&wrow[cc];
      acc += xp[cc] * w4.x + xp[cc + 1] * w4.y + xp[cc + 2] * w4.z + xp[cc + 3] * w4.w;
    }
    part[ks][el] = acc;
    __syncthreads();
    if (ks == 0) {
      float s = part[0][el] + part[1][el] + part[2][el] + part[3][el];
      s = (s + bpq[e]) * SCALING;
      const int h = e >> 6, d = e & 63;
      pq_s[((size_t)(ib * NH + h) * NP + p) * HD + d] = s;
    }
  } else {
    const int tid = (b - 512) * 256 + t;
    const int NT = 1024 * 256;
    for (int i = tid; i < 1835008; i += NT) {
      const float* src; unsigned short* dst; int off;
      if (i < 1048576)      { src = query; dst = qbf;             off = i; }
      else if (i < 1310720) { src = Wk;    dst = wkvbf;           off = i - 1048576; }
      else if (i < 1572864) { src = Wv;    dst = wkvbf + 1048576; off = i - 1310720; }
      else                  { src = Wo;    dst = wobf;            off = i - 1572864; }
      const float4 v = *(const float4*)&src[(size_t)off * 4];
      ushort4 o;
      o.x = f2bf(v.x); o.y = f2bf(v.y); o.z = f2bf(v.z); o.w = f2bf(v.w);
      *(ushort4*)&dst[(size_t)off * 4] = o;
    }
    if (tid < 512) {
      const int j = tid * 4;
      if (j < 1024) *(float4*)&bkv[j] = *(const float4*)&bk[j];
      else          *(float4*)&bkv[j] = *(const float4*)&bv[j - 1024];
    }
  }
}

// ---------------- KV GEMM: 128x64 tiles, double-buffered LDS, dual bf16 out ----------------
__global__ __launch_bounds__(256) void kv_gemm_kernel(
    const unsigned short* __restrict__ Xb, const unsigned short* __restrict__ Wb,
    const float* __restrict__ bias, unsigned short* __restrict__ Y0,
    unsigned short* __restrict__ Y1)
{
  __shared__ unsigned short As[2][4096];   // [128][32]
  __shared__ unsigned short Bs[2][2048];   // [64][32]
  const int t = threadIdx.x;
  const int L = blockIdx.x;
  const int b = (L & 7) * 128 + (L >> 3);           // XCD-bijective swizzle (1024 % 8 == 0)
  const int m0 = (b >> 5) * 128, n0 = (b & 31) * 64;
  const int lane = t & 63, w = t >> 6, wr = w >> 1, wc = w & 1;
  const int lr = lane & 15, lg = lane >> 4;
  const int srow = t >> 2, scol = (t & 3) << 3;
  const unsigned short* xa = &Xb[(size_t)(m0 + srow) * 1024 + scol];
  const unsigned short* xc = &Xb[(size_t)(m0 + srow + 64) * 1024 + scol];
  const unsigned short* wp = &Wb[(size_t)(n0 + srow) * 1024 + scol];
  f32x4 acc[4][2] = {};

  gload16(xa, &As[0][t * 8]);
  gload16(xc, &As[0][2048 + t * 8]);
  gload16(wp, &Bs[0][t * 8]);
  __syncthreads();
  int cur = 0;
  for (int ks = 0; ks < 32; ++ks) {
    if (ks < 31) {
      const int k1 = (ks + 1) * 32;
      gload16(xa + k1, &As[cur ^ 1][t * 8]);
      gload16(xc + k1, &As[cur ^ 1][2048 + t * 8]);
      gload16(wp + k1, &Bs[cur ^ 1][t * 8]);
    }
    short8 av[4], bv[2];
    #pragma unroll
    for (int m = 0; m < 4; ++m) av[m] = *(const short8*)&As[cur][(wr * 64 + m * 16 + lr) * 32 + lg * 8];
    #pragma unroll
    for (int n = 0; n < 2; ++n) bv[n] = *(const short8*)&Bs[cur][(wc * 32 + n * 16 + lr) * 32 + lg * 8];
    #pragma unroll
    for (int m = 0; m < 4; ++m)
      #pragma unroll
      for (int n = 0; n < 2; ++n)
        acc[m][n] = __builtin_amdgcn_mfma_f32_16x16x32_bf16(av[m], bv[n], acc[m][n], 0, 0, 0);
    __syncthreads();
    cur ^= 1;
  }

  unsigned short* dst = (n0 < 1024) ? Y0 : Y1;
  #pragma unroll
  for (int n = 0; n < 2; ++n) {
    const int gcol = n0 + wc * 32 + n * 16 + lr;
    const float bcol = bias[gcol];
    const int lcol = gcol & 1023;
    #pragma unroll
    for (int m = 0; m < 4; ++m) {
      const int row0 = m0 + wr * 64 + m * 16 + lg * 4;
      #pragma unroll
      for (int q = 0; q < 4; ++q)
        dst[(size_t)(row0 + q) * 1024 + lcol] = f2bf(acc[m][n][q] + bcol);
    }
  }
}

// ---------------- pattn logits + fused per-chunk column max ----------------
__global__ __launch_bounds__(256) void pattn_kernel(
    const float* __restrict__ query, const float* __restrict__ pq_s,
    float* __restrict__ pe, float* __restrict__ redm)
{
  const int c = blockIdx.x, bh = blockIdx.y;
  const int ib = bh >> 4, h = bh & 15;
  const int t = threadIdx.x;
  const int i0 = c * CHK;
  __shared__ float qs[CHK][68];
  __shared__ float ps[NP][68];
  __shared__ float red[16][17];
  for (int l = t; l < CHK * 16; l += 256) {
    const int i = l >> 4, d4 = (l & 15) << 2;
    *(float4*)&qs[i][d4] =
        *(const float4*)&query[((size_t)(i0 + i) * BATCH + ib) * EMB + h * HD + d4];
  }
  {
    const int pp = t >> 4, d4 = (t & 15) << 2;
    *(float4*)&ps[pp][d4] = *(const float4*)&pq_s[((size_t)bh * NP + pp) * HD + d4];
  }
  __syncthreads();
  const int p = t & 15, ig = t >> 4;
  float mx = -3.0e38f;
  for (int rep = 0; rep < 4; ++rep) {
    const int i = rep * 16 + ig;
    float acc = 0.f;
    for (int d = 0; d < HD; ++d) acc += qs[i][d] * ps[p][d];
    pe[(size_t)bh * (N_TOK * NP) + (size_t)(i0 + i) * NP + p] = acc;
    mx = fmaxf(mx, acc);
  }
  red[ig][p] = mx;
  __syncthreads();
  if (t < 16) {
    float m2 = red[0][t];
    #pragma unroll
    for (int g2 = 1; g2 < 16; ++g2) m2 = fmaxf(m2, red[g2][t]);
    redm[((size_t)bh * NCHK + c) * 16 + t] = m2;
  }
}

// ---------------- fused exp + per-chunk totals via MFMA ----------------
__global__ __launch_bounds__(256) void totals_mfma_kernel(
    const unsigned short* __restrict__ Kbf, const unsigned short* __restrict__ Vbf,
    float* __restrict__ pe, const float* __restrict__ redm,
    float* __restrict__ Tk, float* __restrict__ Tv, float* __restrict__ Tsc)
{
  const int c = blockIdx.x, bh = blockIdx.y;
  const int ib = bh >> 4, h = bh & 15;
  const int t = threadIdx.x;
  const int i0 = c * CHK;
  const int lane = t & 63, w = t >> 6;
  const int lr = lane & 15, lg = lane >> 4;

  __shared__ unsigned short KT[64][80];
  __shared__ unsigned short VT[64][80];
  __shared__ unsigned short EbT[16][80];
  __shared__ float Ef[64][20];
  __shared__ float ms[16];
  __shared__ float tspart[4][16];

  if (t < 16) {
    float m2 = -3.0e38f;
    #pragma unroll
    for (int s = 0; s < NCHK; ++s) m2 = fmaxf(m2, redm[((size_t)bh * NCHK + s) * 16 + t]);
    ms[t] = m2;
  }
  __syncthreads();

  #pragma unroll
  for (int it = 0; it < 2; ++it) {
    const int task = t + it * 256;
    const int j = task & 63, dg = task >> 6;
    const size_t g = ((size_t)(i0 + j) * BATCH + ib) * EMB + h * HD + dg * 8;
    const uint4 ku = *(const uint4*)&Kbf[g];
    const uint4 vu = *(const uint4*)&Vbf[g];
    const unsigned short* kk = (const unsigned short*)&ku;
    const unsigned short* vv = (const unsigned short*)&vu;
    #pragma unroll
    for (int e = 0; e < 8; ++e) { KT[dg * 8 + e][j] = kk[e]; VT[dg * 8 + e][j] = vv[e]; }
  }
  {
    const int j = t >> 2, p0 = (t & 3) << 2;
    const size_t gi = (size_t)bh * (N_TOK * NP) + (size_t)(i0 + j) * NP + p0;
    float4 l4 = *(const float4*)&pe[gi];
    l4.x = expf(l4.x - ms[p0]);     l4.y = expf(l4.y - ms[p0 + 1]);
    l4.z = expf(l4.z - ms[p0 + 2]); l4.w = expf(l4.w - ms[p0 + 3]);
    *(float4*)&pe[gi] = l4;
    Ef[j][p0] = l4.x; Ef[j][p0 + 1] = l4.y; Ef[j][p0 + 2] = l4.z; Ef[j][p0 + 3] = l4.w;
    EbT[p0][j] = f2bf(l4.x); EbT[p0 + 1][j] = f2bf(l4.y);
    EbT[p0 + 2][j] = f2bf(l4.z); EbT[p0 + 3][j] = f2bf(l4.w);
  }
  __syncthreads();

  if (t < 64) {
    const int p = t & 15, qq = t >> 4;
    float s = 0.f;
    #pragma unroll
    for (int jj = 0; jj < 16; ++jj) s += Ef[qq * 16 + jj][p];
    tspart[qq][p] = s;
  }

  short8 ae0 = *(const short8*)&EbT[lr][lg * 8];
  short8 ae1 = *(const short8*)&EbT[lr][32 + lg * 8];
  const size_t tb = (size_t)(bh * NCHK + c) * 1024;

  {
    f32x4 ka = {};
    short8 bk0 = *(const short8*)&KT[w * 16 + lr][lg * 8];
    short8 bk1 = *(const short8*)&KT[w * 16 + lr][32 + lg * 8];
    ka = __builtin_amdgcn_mfma_f32_16x16x32_bf16(ae0, bk0, ka, 0, 0, 0);
    ka = __builtin_amdgcn_mfma_f32_16x16x32_bf16(ae1, bk1, ka, 0, 0, 0);
    #pragma unroll
    for (int q = 0; q < 4; ++q) Tk[tb + (lg * 4 + q) * 64 + w * 16 + lr] = ka[q];
  }
  {
    f32x4 va = {};
    short8 av0 = *(const short8*)&VT[w * 16 + lr][lg * 8];
    short8 av1 = *(const short8*)&VT[w * 16 + lr][32 + lg * 8];
    va = __builtin_amdgcn_mfma_f32_16x16x32_bf16(av0, ae0, va, 0, 0, 0);
    va = __builtin_amdgcn_mfma_f32_16x16x32_bf16(av1, ae1, va, 0, 0, 0);
    #pragma unroll
    for (int q = 0; q < 4; ++q) Tv[tb + (w * 16 + lg * 4 + q) * 16 + lr] = va[q];
  }
  __syncthreads();
  if (t < 16)
    Tsc[(size_t)(bh * NCHK + c) * 16 + t] =
        tspart[0][t] + tspart[1][t] + tspart[2][t] + tspart[3][t];
}

// ---------------- exclusive scan over chunks ----------------
__global__ __launch_bounds__(256) void chunk_scan_kernel(
    float* __restrict__ Tk, float* __restrict__ Tv, float* __restrict__ Ts)
{
  const int bh = blockIdx.x, y = blockIdx.y, t = threadIdx.x;
  const int slot = y * 256 + t;
  float* arr = (slot < 1024) ? Tk : Tv;
  const int e = slot & 1023;
  const size_t base = (size_t)bh * (NCHK * 1024) + e;
  float v[NCHK];
  #pragma unroll
  for (int c = 0; c < NCHK; ++c) v[c] = arr[base + (size_t)c * 1024];
  float run = 0.f;
  #pragma unroll
  for (int c = 0; c < NCHK; ++c) { arr[base + (size_t)c * 1024] = run; run += v[c]; }
  if (y == 7 && t < 16) {
    const size_t sb = (size_t)bh * (NCHK * 16) + t;
    float s[NCHK];
    #pragma unroll
    for (int c = 0; c < NCHK; ++c) s[c] = Ts[sb + c * 16];
    float rs = 0.f;
    #pragma unroll
    for (int c = 0; c < NCHK; ++c) { Ts[sb + c * 16] = rs; rs += s[c]; }
  }
}

// ---------------- within-chunk causal attention via MFMA ----------------
__global__ __launch_bounds__(256) void attn_mfma_kernel(
    const unsigned short* __restrict__ qbf, const unsigned short* __restrict__ Kbf,
    const unsigned short* __restrict__ Vbf, const float* __restrict__ pe,
    const float* __restrict__ Tk, const float* __restrict__ Tv,
    const float* __restrict__ Ts, float* __restrict__ aw_buf,
    unsigned short* __restrict__ outpre)
{
  const int c = blockIdx.x, bh = blockIdx.y;
  const int ib = bh >> 4, h = bh & 15;
  const int t = threadIdx.x;
  const int i0 = c * CHK;
  const int lane = t & 63, w = t >> 6;
  const int ws = w * 16;
  const int lr = lane & 15, lg = lane >> 4;
  const int nsl = (w >> 1) + 1;

  __shared__ unsigned short Qb[64][80];
  __shared__ unsigned short Kb[64][80];
  __shared__ unsigned short VT[64][80];
  __shared__ unsigned short Ab[64][80];
  __shared__ unsigned short Eb[64][40];
  __shared__ unsigned short EbT[16][80];
  __shared__ unsigned short Nbt[16][80];
  __shared__ unsigned short Mbt[64][40];
  __shared__ unsigned short Gb[64][40];
  __shared__ float Sbf[16];

  #pragma unroll
  for (int it = 0; it < 2; ++it) {
    const int task = t + it * 256;
    const int i = task >> 3, d0 = (task & 7) << 3;
    const size_t g = ((size_t)(i0 + i) * BATCH + ib) * EMB + h * HD + d0;
    *(uint4*)&Qb[i][d0] = *(const uint4*)&qbf[g];
    *(uint4*)&Kb[i][d0] = *(const uint4*)&Kbf[g];
  }
  #pragma unroll
  for (int it = 0; it < 2; ++it) {
    const int task = t + it * 256;
    const int j = task & 63, dg = task >> 6;
    const size_t g = ((size_t)(i0 + j) * BATCH + ib) * EMB + h * HD + dg * 8;
    const uint4 vu = *(const uint4*)&Vbf[g];
    const unsigned short* vv = (const unsigned short*)&vu;
    #pragma unroll
    for (int e = 0; e < 8; ++e) VT[dg * 8 + e][j] = vv[e];
  }
  {
    const int j = t >> 2, p0 = (t & 3) << 2;
    const float4 e4 = *(const float4*)&pe[(size_t)bh * (N_TOK * NP) + (size_t)(i0 + j) * NP + p0];
    const unsigned short b0 = f2bf(e4.x), b1 = f2bf(e4.y), b2 = f2bf(e4.z), b3 = f2bf(e4.w);
    Eb[j][p0] = b0; Eb[j][p0 + 1] = b1; Eb[j][p0 + 2] = b2; Eb[j][p0 + 3] = b3;
    Eb[j][p0 + 16] = 0; Eb[j][p0 + 17] = 0; Eb[j][p0 + 18] = 0; Eb[j][p0 + 19] = 0;
    EbT[p0][j] = b0; EbT[p0 + 1][j] = b1; EbT[p0 + 2][j] = b2; EbT[p0 + 3][j] = b3;
  }
  {
    const int p = t >> 4, d0 = (t & 15) << 2;
    const float4 v = *(const float4*)&Tk[(size_t)(bh * NCHK + c) * 1024 + p * 64 + d0];
    Nbt[p][d0] = f2bf(v.x); Nbt[p][d0 + 1] = f2bf(v.y);
    Nbt[p][d0 + 2] = f2bf(v.z); Nbt[p][d0 + 3] = f2bf(v.w);
  }
  {
    const int d = t >> 2, p0 = (t & 3) << 2;
    const float4 v = *(const float4*)&Tv[(size_t)(bh * NCHK + c) * 1024 + d * 16 + p0];
    Mbt[d][p0] = f2bf(v.x); Mbt[d][p0 + 1] = f2bf(v.y);
    Mbt[d][p0 + 2] = f2bf(v.z); Mbt[d][p0 + 3] = f2bf(v.w);
    Mbt[d][p0 + 16] = 0; Mbt[d][p0 + 17] = 0; Mbt[d][p0 + 18] = 0; Mbt[d][p0 + 19] = 0;
  }
  if (t < 16) Sbf[t] = Ts[(size_t)(bh * NCHK + c) * 16 + t];
  __syncthreads();

  short8 avq0 = *(const short8*)&Qb[ws + lr][lg * 8];
  short8 avq1 = *(const short8*)&Qb[ws + lr][32 + lg * 8];

  f32x4 sacc[4] = {};
  for (int n = 0; n <= w; ++n) {
    short8 bk0 = *(const short8*)&Kb[n * 16 + lr][lg * 8];
    short8 bk1 = *(const short8*)&Kb[n * 16 + lr][32 + lg * 8];
    sacc[n] = __builtin_amdgcn_mfma_f32_16x16x32_bf16(avq0, bk0, sacc[n], 0, 0, 0);
    sacc[n] = __builtin_amdgcn_mfma_f32_16x16x32_bf16(avq1, bk1, sacc[n], 0, 0, 0);
  }
  #pragma unroll
  for (int q = 0; q < 4; ++q)
    if (lr >= lg * 4 + q) sacc[w][q] = 0.f;
  for (int n = 0; n < 2 * nsl; ++n)
    #pragma unroll
    for (int q = 0; q < 4; ++q)
      Ab[ws + lg * 4 + q][n * 16 + lr] = f2bf(sacc[n][q]);

  short8 bve0 = *(const short8*)&EbT[lr][lg * 8];
  short8 bve1 = *(const short8*)&EbT[lr][32 + lg * 8];

  f32x4 wacc = {};
  {
    short8 bn0 = *(const short8*)&Nbt[lr][lg * 8];
    short8 bn1 = *(const short8*)&Nbt[lr][32 + lg * 8];
    wacc = __builtin_amdgcn_mfma_f32_16x16x32_bf16(avq0, bn0, wacc, 0, 0, 0);
    wacc = __builtin_amdgcn_mfma_f32_16x16x32_bf16(avq1, bn1, wacc, 0, 0, 0);
  }
  for (int ks = 0; ks < nsl; ++ks) {
    short8 aa = *(const short8*)&Ab[ws + lr][ks * 32 + lg * 8];
    wacc = __builtin_amdgcn_mfma_f32_16x16x32_bf16(aa, ks ? bve1 : bve0, wacc, 0, 0, 0);
  }
  const float s0 = Sbf[lr];
  f32x4 scacc = {s0, s0, s0, s0};
  for (int ks = 0; ks < nsl; ++ks) {
    const int jb = ks * 32 + lg * 8;
    const int irow = ws + lr;
    short8 ones;
    #pragma unroll
    for (int e = 0; e < 8; ++e) ones[e] = (short)((jb + e < irow) ? 0x3F80 : 0);
    scacc = __builtin_amdgcn_mfma_f32_16x16x32_bf16(ones, ks ? bve1 : bve0, scacc, 0, 0, 0);
  }

  const size_t awbase = (size_t)bh * (N_TOK * NP) + (size_t)i0 * NP;
  #pragma unroll
  for (int q = 0; q < 4; ++q) {
    const int il = lg * 4 + q;
    const float ssum = scacc[q];
    const float ssafe = (ssum > 0.f) ? ssum : 1.f;
    const float wv = SCALING * wacc[q] / ssafe;
    float m = wv;
    #pragma unroll
    for (int off = 1; off < 16; off <<= 1) m = fmaxf(m, __shfl_xor(m, off, 64));
    const float e = expf(wv - m);
    float ss = e;
    #pragma unroll
    for (int off = 1; off < 16; off <<= 1) ss += __shfl_xor(ss, off, 64);
    const float aw = e / ss;
    aw_buf[awbase + (size_t)(ws + il) * NP + lr] = aw;
    const float g = aw / ssafe;
    Gb[ws + il][lr] = f2bf(g);
    Gb[ws + il][lr + 16] = 0;
  }

  short8 ga = *(const short8*)&Gb[ws + lr][lg * 8];
  f32x4 bacc[4] = {};
  for (int n = 0; n <= w; ++n) {
    short8 be = *(const short8*)&Eb[n * 16 + lr][lg * 8];
    bacc[n] = __builtin_amdgcn_mfma_f32_16x16x32_bf16(ga, be, bacc[n], 0, 0, 0);
  }
  #pragma unroll
  for (int q = 0; q < 4; ++q)
    if (lr >= lg * 4 + q) bacc[w][q] = 0.f;
  for (int n = 0; n < 2 * nsl; ++n)
    #pragma unroll
    for (int q = 0; q < 4; ++q)
      Ab[ws + lg * 4 + q][n * 16 + lr] = f2bf(bacc[n][q]);

  f32x4 oacc[4] = {};
  #pragma unroll
  for (int dn = 0; dn < 4; ++dn) {
    short8 bm = *(const short8*)&Mbt[dn * 16 + lr][lg * 8];
    oacc[dn] = __builtin_amdgcn_mfma_f32_16x16x32_bf16(ga, bm, oacc[dn], 0, 0, 0);
  }
  for (int ks = 0; ks < nsl; ++ks) {
    short8 ab = *(const short8*)&Ab[ws + lr][ks * 32 + lg * 8];
    #pragma unroll
    for (int dn = 0; dn < 4; ++dn) {
      short8 bv = *(const short8*)&VT[dn * 16 + lr][ks * 32 + lg * 8];
      oacc[dn] = __builtin_amdgcn_mfma_f32_16x16x32_bf16(ab, bv, oacc[dn], 0, 0, 0);
    }
  }

  #pragma unroll
  for (int dn = 0; dn < 4; ++dn)
    #pragma unroll
    for (int q = 0; q < 4; ++q) {
      const int i = ws + lg * 4 + q;
      const int d = dn * 16 + lr;
      outpre[((size_t)(i0 + i) * BATCH + ib) * EMB + h * HD + d] = f2bf(oacc[dn][q]);
    }
}

// ---------------- O-GEMM (128x64, dbuf, f32 out) + aw mean over heads ----------------
__global__ __launch_bounds__(256) void o_aw_kernel(
    const unsigned short* __restrict__ Xb, const unsigned short* __restrict__ Wb,
    const float* __restrict__ bias, float* __restrict__ Yf,
    const float* __restrict__ aw_buf, float* __restrict__ out_aw)
{
  __shared__ unsigned short As[2][4096];
  __shared__ unsigned short Bs[2][2048];
  const int L = blockIdx.x, t = threadIdx.x;
  if (L < 512) {
    const int b = (L & 7) * 64 + (L >> 3);          // XCD-bijective swizzle (512 % 8 == 0)
    const int m0 = (b >> 4) * 128, n0 = (b & 15) * 64;
    const int lane = t & 63, w = t >> 6, wr = w >> 1, wc = w & 1;
    const int lr = lane & 15, lg = lane >> 4;
    const int srow = t >> 2, scol = (t & 3) << 3;
    const unsigned short* xa = &Xb[(size_t)(m0 + srow) * 1024 + scol];
    const unsigned short* xc = &Xb[(size_t)(m0 + srow + 64) * 1024 + scol];
    const unsigned short* wp = &Wb[(size_t)(n0 + srow) * 1024 + scol];
    f32x4 acc[4][2] = {};

    gload16(xa, &As[0][t * 8]);
    gload16(xc, &As[0][2048 + t * 8]);
    gload16(wp, &Bs[0][t * 8]);
    __syncthreads();
    int cur = 0;
    for (int ks = 0; ks < 32; ++ks) {
      if (ks < 31) {
        const int k1 = (ks + 1) * 32;
        gload16(xa + k1, &As[cur ^ 1][t * 8]);
        gload16(xc + k1, &As[cur ^ 1][2048 + t * 8]);
        gload16(wp + k1, &Bs[cur ^ 1][t * 8]);
      }
      short8 av[4], bv[2];
      #pragma unroll
      for (int m = 0; m < 4; ++m) av[m] = *(const short8*)&As[cur][(wr * 64 + m * 16 + lr) * 32 + lg * 8];
      #pragma unroll
      for (int n = 0; n < 2; ++n) bv[n] = *(const short8*)&Bs[cur][(wc * 32 + n * 16 + lr) * 32 + lg * 8];
      #pragma unroll
      for (int m = 0; m < 4; ++m)
        #pragma unroll
        for (int n = 0; n < 2; ++n)
          acc[m][n] = __builtin_amdgcn_mfma_f32_16x16x32_bf16(av[m], bv[n], acc[m][n], 0, 0, 0);
      __syncthreads();
      cur ^= 1;
    }
    #pragma unroll
    for (int n = 0; n < 2; ++n) {
      const int gcol = n0 + wc * 32 + n * 16 + lr;
      const float bcol = bias[gcol];
      #pragma unroll
      for (int m = 0; m < 4; ++m) {
        const int row0 = m0 + wr * 64 + m * 16 + lg * 4;
        #pragma unroll
        for (int q = 0; q < 4; ++q)
          Yf[(size_t)(row0 + q) * 1024 + gcol] = acc[m][n][q] + bcol;
      }
    }
  } else {
    const int idx = (L - 512) * 256 + t;
    const int p = idx & 15;
    const int i = (idx >> 4) & 2047;
    const int ib = idx >> 15;
    float s = 0.f;
    for (int hh = 0; hh < NH; ++hh)
      s += aw_buf[((size_t)(ib * NH + hh) * N_TOK + i) * NP + p];
    out_aw[idx] = s * (1.f / 16.f);
  }
}

extern "C" void kernel_launch(void* const* d_in, const int* in_sizes, int n_in,
                              void* d_out, int out_size, void* d_ws, size_t ws_size,
                              hipStream_t stream) {
  const float* query  = (const float*)d_in[0];
  const float* pquery = (const float*)d_in[1];
  const float* Wpq    = (const float*)d_in[2];
  const float* bpq    = (const float*)d_in[3];
  const float* Wk     = (const float*)d_in[4];
  const float* bk     = (const float*)d_in[5];
  const float* Wv     = (const float*)d_in[6];
  const float* bv     = (const float*)d_in[7];
  const float* Wo     = (const float*)d_in[8];
  const float* bo     = (const float*)d_in[9];
  float* out = (float*)d_out;
  float* ws  = (float*)d_ws;

  float* pq_s   = ws;                       // 32768
  float* pe     = pq_s + 32768;             // 1048576
  float* aw_buf = pe + 1048576;             // 1048576
  float* Tk     = aw_buf + 1048576;         // 1048576
  float* Tv     = Tk + 1048576;             // 1048576
  float* Ts     = Tv + 1048576;             // 16384
  float* redm   = Ts + 16384;               // 16384
  float* bkv    = redm + 16384;             // 2048
  unsigned short* qbf   = (unsigned short*)(bkv + 2048);
  unsigned short* Kbf   = qbf + 4194304;
  unsigned short* Vbf   = Kbf + 4194304;
  unsigned short* wkvbf = Vbf + 4194304;    // 2097152
  unsigned short* wobf  = wkvbf + 2097152;  // 1048576
  unsigned short* opbf  = wobf + 1048576;   // 4194304

  prep_pq_kernel<<<1536, 256, 0, stream>>>(query, Wk, Wv, Wo, bk, bv, pquery, Wpq, bpq,
                                           qbf, wkvbf, wobf, bkv, pq_s);
  kv_gemm_kernel<<<1024, 256, 0, stream>>>(qbf, wkvbf, bkv, Kbf, Vbf);
  pattn_kernel<<<dim3(NCHK, BHN), 256, 0, stream>>>(query, pq_s, pe, redm);
  totals_mfma_kernel<<<dim3(NCHK, BHN), 256, 0, stream>>>(Kbf, Vbf, pe, redm, Tk, Tv, Ts);
  chunk_scan_kernel<<<dim3(BHN, 8), 256, 0, stream>>>(Tk, Tv, Ts);
  attn_mfma_kernel<<<dim3(NCHK, BHN), 256, 0, stream>>>(qbf, Kbf, Vbf, pe, Tk, Tv, Ts,
                                                        aw_buf, opbf);
  o_aw_kernel<<<768, 256, 0, stream>>>(opbf, wobf, bo, out, aw_buf, out + 4194304);
}